// Round 1
// baseline (106.620 us; speedup 1.0000x reference)
//
#include <hip/hip_runtime.h>

#define Bn   4
#define CIN  32
#define COUT 32
#define CG   8
#define Hh   128
#define Ww   128
#define KK   5
#define HW   (Hh * Ww)

// One thread = one pixel x one half of the output channels (16 of 32).
// blockIdx.y = channel half -> weight addresses are uniform across the wave
// (scalar-load eligible); x/guide accesses coalesce along n.
__global__ __launch_bounds__(256, 2) void pac_fp32(
    const float* __restrict__ x, const float* __restrict__ guide,
    const float* __restrict__ weight, const float* __restrict__ bias,
    float* __restrict__ out)
{
    const int p    = blockIdx.x * 256 + threadIdx.x;   // pixel id 0..65535
    const int half = blockIdx.y;                       // 0/1 -> o in [16h, 16h+16)
    const int n = p & (Ww - 1);
    const int m = (p >> 7) & (Hh - 1);
    const int b = p >> 14;

    // ---- adaptive kernel from guide ----
    const float* gb = guide + (size_t)b * CG * HW + m * Ww + n;
    float center[CG];
#pragma unroll
    for (int c = 0; c < CG; ++c) center[c] = gb[c * HW];

    float kern[KK * KK];
#pragma unroll
    for (int k = 0; k < KK; ++k) {
        const int dm = k - 2;
        const bool rowok = ((unsigned)(m + dm) < (unsigned)Hh);
#pragma unroll
        for (int l = 0; l < KK; ++l) {
            const int dn = l - 2;
            const bool ok = rowok && ((unsigned)(n + dn) < (unsigned)Ww);
            float ss = 0.f;
#pragma unroll
            for (int c = 0; c < CG; ++c) {
                // zero-padded guide patch: OOB tap reads 0, d = -center
                float gv = ok ? gb[c * HW + dm * Ww + dn] : 0.f;
                float d = gv - center[c];
                ss = fmaf(d, d, ss);
            }
            kern[k * KK + l] = __expf(-0.5f * ss);
        }
    }

    // ---- pixel-adaptive convolution ----
    float acc[16];
#pragma unroll
    for (int o = 0; o < 16; ++o) acc[o] = 0.f;

    const int obase = half * 16;
    const float* xb = x + (size_t)b * CIN * HW + m * Ww + n;
    const float* wb = weight + (size_t)obase * (CIN * KK * KK);

    for (int j = 0; j < CIN; ++j) {
        // weighted input patch for this input channel (OOB x-taps contribute 0)
        float xv[KK * KK];
#pragma unroll
        for (int k = 0; k < KK; ++k) {
            const int dm = k - 2;
            const bool rowok = ((unsigned)(m + dm) < (unsigned)Hh);
#pragma unroll
            for (int l = 0; l < KK; ++l) {
                const int dn = l - 2;
                const bool ok = rowok && ((unsigned)(n + dn) < (unsigned)Ww);
                float v = ok ? xb[j * HW + dm * Ww + dn] : 0.f;
                xv[k * KK + l] = v * kern[k * KK + l];
            }
        }
        const float* wj = wb + j * (KK * KK);
#pragma unroll
        for (int o = 0; o < 16; ++o) {
            const float* wo = wj + (size_t)o * (CIN * KK * KK);  // w[obase+o][j][:][:], 25 contiguous
            float a = acc[o];
#pragma unroll
            for (int t = 0; t < KK * KK; ++t)
                a = fmaf(xv[t], wo[t], a);
            acc[o] = a;
        }
    }

    float* op = out + (size_t)b * COUT * HW + m * Ww + n;
#pragma unroll
    for (int o = 0; o < 16; ++o)
        op[(size_t)(obase + o) * HW] = acc[o] + bias[obase + o];
}

extern "C" void kernel_launch(void* const* d_in, const int* in_sizes, int n_in,
                              void* d_out, int out_size, void* d_ws, size_t ws_size,
                              hipStream_t stream) {
    const float* x      = (const float*)d_in[0];
    const float* guide  = (const float*)d_in[1];
    const float* weight = (const float*)d_in[2];
    const float* bias   = (const float*)d_in[3];
    float* out = (float*)d_out;

    dim3 grid(Bn * HW / 256, 2);
    pac_fp32<<<grid, dim3(256), 0, stream>>>(x, guide, weight, bias, out);
}